// Round 2
// baseline (62.589 us; speedup 1.0000x reference)
//
#include <hip/hip_runtime.h>
#include <stdint.h>

#define D 128
#define ROWS 32
#define G 32
#define JPL 4
#define NTHREADS (ROWS * G)  // 1024

typedef float f2 __attribute__((ext_vector_type(2)));

__device__ __forceinline__ uint16_t f2bf(float f) {
  uint32_t u = __float_as_uint(f);
  u += 0x7fffu + ((u >> 16) & 1u);  // RNE
  return (uint16_t)(u >> 16);
}

__device__ __forceinline__ f2 unpk(uint32_t u) {
  f2 r;
  r.x = __uint_as_float(u << 16);
  r.y = __uint_as_float(u & 0xffff0000u);
  return r;
}

// xor-16 lane exchange within each 32-lane half (BitMode: xor=0x10, and=0x1F)
__device__ __forceinline__ float swz16(float v) {
  return __int_as_float(__builtin_amdgcn_ds_swizzle(__float_as_int(v), 0x401F));
}

#define DPP_ADD(v, ctrl)                                                          \
  (v) += __int_as_float(__builtin_amdgcn_update_dpp(0, __float_as_int(v), (ctrl), \
                                                    0xf, 0xf, true))

__global__ __launch_bounds__(NTHREADS, 4)
void iaf_kernel(const float* __restrict__ x, const float* __restrict__ W1,
                const float* __restrict__ b1, const float* __restrict__ Wmu,
                const float* __restrict__ bmu, const float* __restrict__ Wls,
                const float* __restrict__ bls, float* __restrict__ out, int B) {
  __shared__ uint16_t wmu_l[D][D];  // [i][j] = bf16(Wmu[i][j]) masked (j<i)
  __shared__ uint16_t wls_l[D][D];  // [i][j] = bf16(Wls[i][j]) masked (j<i)
  __shared__ uint16_t w1c_l[D][D];  // [i][j] = bf16(W1[j][i]) masked (j>i): column i as a row
  __shared__ float xs[ROWS][D + 1];
  __shared__ f2 bias_l[D];          // {bmu[i], bls[i]}

  const int tid = threadIdx.x;
  const int r0 = blockIdx.x * ROWS;

  // ---- stage weights (masks baked in), coalesced global reads ----
  for (int idx = tid; idx < D * D; idx += NTHREADS) {
    const int p = idx >> 7, q = idx & (D - 1);
    wmu_l[p][q] = f2bf((q < p) ? Wmu[idx] : 0.f);
    wls_l[p][q] = f2bf((q < p) ? Wls[idx] : 0.f);
    w1c_l[q][p] = f2bf((p > q) ? W1[idx] : 0.f);  // W1[p][q] -> column-q row
  }
  if (tid < D) {
    f2 b;
    b.x = bmu[tid];
    b.y = bls[tid];
    bias_l[tid] = b;
  }
  for (int idx = tid; idx < ROWS * D; idx += NTHREADS) {
    xs[idx >> 7][idx & (D - 1)] = x[(size_t)r0 * D + idx];
  }
  __syncthreads();

  const int g = tid >> 5;          // row within block (0..31)
  const int sub = tid & 31;        // lane within 32-lane group
  const bool hi = (sub & 16) != 0; // upper half of the group
  const int j0 = sub * JPL;

  const float4 bv = *reinterpret_cast<const float4*>(&b1[j0]);
  f2 A01, A23;
  A01.x = bv.x; A01.y = bv.y; A23.x = bv.z; A23.y = bv.w;

  float zr[JPL];
  float ldj = 0.f;

#pragma unroll 2
  for (int ib = 0; ib < G; ++ib) {
#pragma unroll
    for (int t = 0; t < JPL; ++t) {
      const int i = ib * JPL + t;
      const uint2 wmuv = *reinterpret_cast<const uint2*>(&wmu_l[i][j0]);
      const uint2 wlsv = *reinterpret_cast<const uint2*>(&wls_l[i][j0]);
      const uint2 w1v  = *reinterpret_cast<const uint2*>(&w1c_l[i][j0]);
      const float xi = xs[g][i];
      const f2 bias = bias_l[i];

      const f2 h01 = __builtin_elementwise_max(A01, (f2)0.f);
      const f2 h23 = __builtin_elementwise_max(A23, (f2)0.f);

      const f2 m2 = __builtin_elementwise_fma(h23, unpk(wmuv.y), h01 * unpk(wmuv.x));
      const f2 l2 = __builtin_elementwise_fma(h23, unpk(wlsv.y), h01 * unpk(wlsv.x));
      const float mu_p = m2.x + m2.y;
      const float ls_p = l2.x + l2.y;

      // folded allreduce over 32 lanes: lo half carries mu, hi half carries ls
      const float mine = hi ? ls_p : mu_p;
      const float give = hi ? mu_p : ls_p;
      float fold = mine + swz16(give);
      DPP_ADD(fold, 0xB1);   // quad_perm xor1
      DPP_ADD(fold, 0x4E);   // quad_perm xor2
      DPP_ADD(fold, 0x124);  // row_ror:4
      DPP_ADD(fold, 0x128);  // row_ror:8
      const float other = swz16(fold);
      const float mu_t = (hi ? other : fold) + bias.x;
      const float ls_t = (hi ? fold : other) + bias.y;

      const float zi = fmaf(xi, __expf(ls_t), mu_t);
      ldj += ls_t;
      if (sub == ib) zr[t] = zi;

      f2 zz; zz.x = zi; zz.y = zi;
      A01 = __builtin_elementwise_fma(zz, unpk(w1v.x), A01);
      A23 = __builtin_elementwise_fma(zz, unpk(w1v.y), A23);
    }
  }

  // ---- write z (each lane stores its 4 contiguous columns) ----
  float4 zv;
  zv.x = zr[0]; zv.y = zr[1]; zv.z = zr[2]; zv.w = zr[3];
  *reinterpret_cast<float4*>(&out[(size_t)(r0 + g) * D + j0]) = zv;
  if (sub == 0) out[(size_t)B * D + r0 + g] = ldj;
}

extern "C" void kernel_launch(void* const* d_in, const int* in_sizes, int n_in,
                              void* d_out, int out_size, void* d_ws, size_t ws_size,
                              hipStream_t stream) {
  const float* x   = (const float*)d_in[0];
  const float* W1  = (const float*)d_in[1];
  const float* b1  = (const float*)d_in[2];
  const float* Wmu = (const float*)d_in[3];
  const float* bmu = (const float*)d_in[4];
  const float* Wls = (const float*)d_in[5];
  const float* bls = (const float*)d_in[6];
  float* out = (float*)d_out;

  const int B = in_sizes[0] / D;           // 8192
  const int grid = (B + ROWS - 1) / ROWS;  // 256
  iaf_kernel<<<grid, NTHREADS, 0, stream>>>(x, W1, b1, Wmu, bmu, Wls, bls, out, B);
}

// Round 3
// 47.991 us; speedup vs baseline: 1.3042x; 1.3042x over previous
//
#include <hip/hip_runtime.h>
#include <stdint.h>

#define D 128
#define NTHR 256
#define RPB 16   // rows per block: 4 waves x 4 rows
#define W1S 136  // padded bf16 row stride (272 B, 16B-aligned, banks spread)

typedef float f2 __attribute__((ext_vector_type(2)));
typedef float f4 __attribute__((ext_vector_type(4)));

__device__ __forceinline__ uint16_t f2bf(float f) {
  uint32_t u = __float_as_uint(f);
  u += 0x7fffu + ((u >> 16) & 1u);  // RNE
  return (uint16_t)(u >> 16);
}
__device__ __forceinline__ f2 unpk(uint32_t u) {
  f2 r;
  r.x = __uint_as_float(u << 16);
  r.y = __uint_as_float(u & 0xffff0000u);
  return r;
}

#define DPP_ADD(v, ctrl)                                                          \
  (v) += __int_as_float(__builtin_amdgcn_update_dpp(0, __float_as_int(v), (ctrl), \
                                                    0xf, 0xf, true))
// all-lanes 16-lane reduction: xor1, xor2, ror4, ror8 (stays within 16-lane row)
#define RED16(v)          \
  do {                    \
    DPP_ADD(v, 0xB1);     \
    DPP_ADD(v, 0x4E);     \
    DPP_ADD(v, 0x124);    \
    DPP_ADD(v, 0x128);    \
  } while (0)

// One recurrence step. WM*/WL* are f32 weight regs for row I (consumed, then
// reloaded for I+2 -> ping-pong prefetch). XE = x[row][I], ZRE/MKE static regs.
#define STEP(I, XE, ZRE, MKE, WM0, WM1, WL0, WL1)                   \
  {                                                                 \
    const float bmu_i = bmu[(I)];                                   \
    const float bls_i = bls[(I)];                                   \
    const f2 h0 = __builtin_elementwise_max(A0, (f2)0.f);           \
    const f2 h1 = __builtin_elementwise_max(A1, (f2)0.f);           \
    const f2 h2 = __builtin_elementwise_max(A2, (f2)0.f);           \
    const f2 h3 = __builtin_elementwise_max(A3, (f2)0.f);           \
    const f2 q0 = h0 * mk0, q1 = h1 * mk1;                          \
    const f2 q2 = h2 * mk2, q3 = h3 * mk3;                          \
    f2 am = q0 * WM0.xy;                                            \
    f2 al = q0 * WL0.xy;                                            \
    am = __builtin_elementwise_fma(q1, WM0.zw, am);                 \
    al = __builtin_elementwise_fma(q1, WL0.zw, al);                 \
    am = __builtin_elementwise_fma(q2, WM1.xy, am);                 \
    al = __builtin_elementwise_fma(q2, WL1.xy, al);                 \
    am = __builtin_elementwise_fma(q3, WM1.zw, am);                 \
    al = __builtin_elementwise_fma(q3, WL1.zw, al);                 \
    float mu_p = am.x + am.y;                                       \
    float ls_p = al.x + al.y;                                       \
    /* prefetch weights for step I+2 into the just-consumed regs */ \
    {                                                               \
      const int pfr = ((I) + 2 < D) ? (I) + 2 : D - 1;              \
      WM0 = *(const f4*)(wmup + pfr * D);                           \
      WM1 = *(const f4*)(wmup + pfr * D + 4);                       \
      WL0 = *(const f4*)(wlsp + pfr * D);                           \
      WL1 = *(const f4*)(wlsp + pfr * D + 4);                       \
    }                                                               \
    RED16(mu_p);                                                    \
    RED16(ls_p);                                                    \
    const float mu_t = mu_p + bmu_i;                                \
    const float ls_t = ls_p + bls_i;                                \
    const float zi = fmaf((XE), __expf(ls_t), mu_t);                \
    ldj += ls_t;                                                    \
    const uint4 wv = *(const uint4*)(w1p + (I)*W1S);                \
    if (own) {                                                      \
      ZRE = zi;                                                     \
      MKE = 1.f;                                                    \
    }                                                               \
    f2 zz;                                                          \
    zz.x = zi;                                                      \
    zz.y = zi;                                                      \
    A0 = __builtin_elementwise_fma(zz, unpk(wv.x), A0);             \
    A1 = __builtin_elementwise_fma(zz, unpk(wv.y), A1);             \
    A2 = __builtin_elementwise_fma(zz, unpk(wv.z), A2);             \
    A3 = __builtin_elementwise_fma(zz, unpk(wv.w), A3);             \
  }

__global__ __launch_bounds__(NTHR, 2)
void iaf_kernel(const float* __restrict__ x, const float* __restrict__ W1,
                const float* __restrict__ b1, const float* __restrict__ Wmu,
                const float* __restrict__ bmu, const float* __restrict__ Wls,
                const float* __restrict__ bls, float* __restrict__ out, int B) {
  __shared__ uint16_t w1c[D * W1S];  // [i][j] = bf16(W1[j][i]), masked j>i

  const int tid = threadIdx.x;
  // ---- stage transposed, masked W1 (only LDS user) ----
  for (int idx = tid; idx < D * D; idx += NTHR) {
    const int p = idx >> 7, q = idx & (D - 1);  // W1[p][q]
    w1c[q * W1S + p] = f2bf((p > q) ? W1[idx] : 0.f);
  }
  __syncthreads();

  const int lane = tid & 63;
  const int m = lane & 15;                       // column-chunk owner (8 cols)
  const int row = blockIdx.x * RPB + (tid >> 4); // 16 rows per block

  const float* __restrict__ xp = x + (size_t)row * D;
  const float* __restrict__ wmup = Wmu + m * 8;
  const float* __restrict__ wlsp = Wls + m * 8;
  const uint16_t* __restrict__ w1p = w1c + m * 8;

  f2 A0, A1, A2, A3;  // a[8m..8m+7]
  {
    const f4 t0 = *(const f4*)(b1 + m * 8);
    const f4 t1 = *(const f4*)(b1 + m * 8 + 4);
    A0 = t0.xy; A1 = t0.zw; A2 = t1.xy; A3 = t1.zw;
  }
  f2 mk0 = (f2)0.f, mk1 = (f2)0.f, mk2 = (f2)0.f, mk3 = (f2)0.f;  // j<i mask
  float zr0 = 0, zr1 = 0, zr2 = 0, zr3 = 0, zr4 = 0, zr5 = 0, zr6 = 0, zr7 = 0;
  float ldj = 0.f;

  // register prefetch buffers: A = even steps, B = odd steps
  f4 wmA0 = *(const f4*)(wmup);
  f4 wmA1 = *(const f4*)(wmup + 4);
  f4 wlA0 = *(const f4*)(wlsp);
  f4 wlA1 = *(const f4*)(wlsp + 4);
  f4 wmB0 = *(const f4*)(wmup + D);
  f4 wmB1 = *(const f4*)(wmup + D + 4);
  f4 wlB0 = *(const f4*)(wlsp + D);
  f4 wlB1 = *(const f4*)(wlsp + D + 4);

  f4 x4a = *(const f4*)(xp);
  f4 x4b;

  for (int ib = 0; ib < 16; ++ib) {
    const int i0 = ib * 8;
    const bool own = (m == ib);
    x4b = *(const f4*)(xp + i0 + 4);  // used at sub-step 4 (distance 4)
    STEP(i0 + 0, x4a.x, zr0, mk0.x, wmA0, wmA1, wlA0, wlA1);
    STEP(i0 + 1, x4a.y, zr1, mk0.y, wmB0, wmB1, wlB0, wlB1);
    STEP(i0 + 2, x4a.z, zr2, mk1.x, wmA0, wmA1, wlA0, wlA1);
    STEP(i0 + 3, x4a.w, zr3, mk1.y, wmB0, wmB1, wlB0, wlB1);
    {
      const int nx = (i0 + 8 < D) ? i0 + 8 : D - 4;  // next block's x (dup-load on tail)
      x4a = *(const f4*)(xp + nx);
    }
    STEP(i0 + 4, x4b.x, zr4, mk2.x, wmA0, wmA1, wlA0, wlA1);
    STEP(i0 + 5, x4b.y, zr5, mk2.y, wmB0, wmB1, wlB0, wlB1);
    STEP(i0 + 6, x4b.z, zr6, mk3.x, wmA0, wmA1, wlA0, wlA1);
    STEP(i0 + 7, x4b.w, zr7, mk3.y, wmB0, wmB1, wlB0, wlB1);
  }

  // ---- stores: each lane owns cols 8m..8m+7 of its row ----
  f4 o0, o1;
  o0.x = zr0; o0.y = zr1; o0.z = zr2; o0.w = zr3;
  o1.x = zr4; o1.y = zr5; o1.z = zr6; o1.w = zr7;
  float* zo = out + (size_t)row * D + m * 8;
  *(f4*)(zo) = o0;
  *(f4*)(zo + 4) = o1;
  if (m == 0) out[(size_t)B * D + row] = ldj;
}

extern "C" void kernel_launch(void* const* d_in, const int* in_sizes, int n_in,
                              void* d_out, int out_size, void* d_ws, size_t ws_size,
                              hipStream_t stream) {
  const float* x   = (const float*)d_in[0];
  const float* W1  = (const float*)d_in[1];
  const float* b1  = (const float*)d_in[2];
  const float* Wmu = (const float*)d_in[3];
  const float* bmu = (const float*)d_in[4];
  const float* Wls = (const float*)d_in[5];
  const float* bls = (const float*)d_in[6];
  float* out = (float*)d_out;

  const int B = in_sizes[0] / D;          // 8192
  const int grid = (B + RPB - 1) / RPB;   // 512
  iaf_kernel<<<grid, NTHR, 0, stream>>>(x, W1, b1, Wmu, bmu, Wls, bls, out, B);
}